// Round 4
// baseline (106.365 us; speedup 1.0000x reference)
//
#include <hip/hip_runtime.h>
#include <math.h>

// CapsShapeLayer: B=256, D=10, M=32, P=36, I=8, O=16, 3 routing iters
#define BB 256
#define DD 10
#define MM 32
#define PP 36
#define II 8
#define OO 16
#define NT 512        // 8 waves -> exactly 2 waves/SIMD; launch_bounds(512,2) -> 256 VGPR budget
#define XS 292        // xs per-m stride = 4*73 (73 odd): m-spanning lanes tile all bank quads
#define RS 37         // rinv row stride: bank = (5m+p)%32, gcd(5,32)=1 -> conflict-free

__device__ __forceinline__ float dot8(const float4 a0, const float4 a1,
                                      const float4 b0, const float4 b1) {
    return a0.x*b0.x + a0.y*b0.y + a0.z*b0.z + a0.w*b0.w
         + a1.x*b1.x + a1.y*b1.y + a1.z*b1.z + a1.w*b1.w;
}

// Fused s+squash for threads t<320: t = (d<<5) | (o<<1) | mh.
// Each thread dots W[d, m in 16-half, o, :] with y[d? m, :]; mh-halves combined
// with shfl_xor(1); squash's sum over o via shfl_xor(2,4,8,16) (bits 1-4 = o).
// Returns squash(s)[d,o] (valid on all 320 lanes; mh pair holds duplicates).
template<int YSTRIDE>
__device__ __forceinline__ float s_squash(const float* __restrict__ W,
                                          const float* __restrict__ y, int tid)
{
    const int d  = tid >> 5;
    const int o  = (tid >> 1) & 15;
    const int mh = tid & 1;
    float acc = 0.f;
    #pragma unroll 8
    for (int j = 0; j < 16; ++j) {
        const int m = (mh << 4) + j;
        const float4* wp = (const float4*)(W + ((size_t)((d*MM + m)*OO + o)) * II);
        const float4* yp = (const float4*)(y + d*YSTRIDE + m*II);
        acc += dot8(wp[0], wp[1], yp[0], yp[1]);
    }
    acc += __shfl_xor(acc, 1, 64);          // combine m-halves
    float sq = acc * acc;
    sq += __shfl_xor(sq, 2, 64);
    sq += __shfl_xor(sq, 4, 64);
    sq += __shfl_xor(sq, 8, 64);
    sq += __shfl_xor(sq, 16, 64);           // sum s^2 over o (16 lanes, same mh)
    return (sq / (1.f + sq)) * (acc / sqrtf(sq + 1e-7f));
}

__global__ void __launch_bounds__(NT, 2) caps_routing(
    const float* __restrict__ x,   // (B, M, P, I)
    const float* __restrict__ W,   // (D, M, O, I)
    float* __restrict__ out)       // (B, D, O)
{
    const int bidx = blockIdx.x;
    const int tid  = threadIdx.x;
    const float* __restrict__ xb = x + (size_t)bidx * (MM*PP*II);

    // b is never stored: b = x . z_acc, recomputed on demand (linear in z).
    __shared__ __align__(16) float xs  [MM*XS];     // 37376 B
    __shared__ __align__(16) float z   [DD*MM*II];  // 10240 B  z1, then z1+z2
    __shared__ __align__(16) float y   [DD*MM*II];  // 10240 B  y scratch (ybar in [0:256])
    __shared__ __align__(16) float rinv[MM*RS];     //  4736 B
    __shared__ __align__(16) float v_l [DD*OO];     //   640 B
    // total 63232 B

    // ---- a: stage x -> LDS ----
    {
        const float4* xg = (const float4*)xb;
        #pragma unroll
        for (int k = 0; k < 5; ++k) {                // 2304 float4 over 512 thr
            const int t = tid + k*NT;
            if (t < MM*72) {
                const int m = t / 72, r = t - m*72;
                *(float4*)(xs + m*XS + 4*r) = xg[t];
            }
        }
    }
    __syncthreads();

    // ---- b: iter1 c = 1/D -> ybar[m,i] = 0.1 * sum_p x  (alias y[0:256]) ----
    if (tid < MM*II) {
        const int m = tid >> 3, i = tid & 7;
        const float* xr = xs + m*XS + i;
        float acc = 0.f;
        #pragma unroll
        for (int p = 0; p < PP; ++p) acc += xr[p*II];
        y[tid] = 0.1f * acc;
    }
    __syncthreads();

    // ---- c: v1 = squash(s1) ----
    if (tid < DD*OO*2) {
        const float v = s_squash<0>(W, y, tid);
        v_l[(tid >> 5)*OO + ((tid >> 1) & 15)] = v;
    }
    __syncthreads();

    // ---- d: z1[d,m,i] = sum_o W[d,m,o,i]*v1[d,o]; zero y for f's atomics ----
    #pragma unroll
    for (int k = 0; k < 5; ++k) {                    // 2560 slots
        const int s = tid + k*NT;
        const int d = s >> 8, mi = s & 255;
        const int m = mi >> 3, i = mi & 7;
        const float* wp = W + ((size_t)(d*MM + m)*OO) * II + i;
        const float* vp = v_l + d*OO;
        float acc = 0.f;
        #pragma unroll
        for (int o = 0; o < OO; ++o) acc += wp[o*II] * vp[o];
        z[s] = acc;
        y[s] = 0.f;
    }
    __syncthreads();

    // ---- e: rinv[m,p] = 1/sum_d exp(x.z1)   (lanes span m -> conflict-free) ----
    #pragma unroll
    for (int k = 0; k < 3; ++k) {                    // 1152 slots
        const int t = tid + k*NT;
        if (t < MM*PP) {
            const int m = t & 31, p = t >> 5;
            const float4* xp = (const float4*)(xs + m*XS + p*II);
            const float4 x0 = xp[0], x1 = xp[1];
            float se = 0.f;
            #pragma unroll
            for (int d = 0; d < DD; ++d) {
                const float4* zp = (const float4*)(z + (d*MM + m)*II);
                se += __expf(dot8(x0, x1, zp[0], zp[1]));
            }
            rinv[m*RS + p] = 1.0f / se;
        }
    }
    __syncthreads();

    // ---- f: y2[d,m,:] += exp(x.z1)*rinv * x  (640 slots = (dm, p-half)) ----
    for (int s = tid; s < DD*MM*2; s += NT) {
        const int dm = s >> 1, ph = s & 1;
        const int m  = dm & 31;
        const float4* zp = (const float4*)(z + dm*II);
        const float4 z0 = zp[0], z1v = zp[1];
        const float* xr = xs + m*XS;
        const float* rr = rinv + m*RS;
        float a0=0.f,a1=0.f,a2=0.f,a3=0.f,a4=0.f,a5=0.f,a6=0.f,a7=0.f;
        const int p0 = ph * (PP/2);
        #pragma unroll 6
        for (int q = 0; q < PP/2; ++q) {
            const int p = p0 + q;
            const float4* xp = (const float4*)(xr + p*II);
            const float4 x0 = xp[0], x1 = xp[1];
            const float e = __expf(dot8(x0, x1, z0, z1v)) * rr[p];
            a0 += e*x0.x; a1 += e*x0.y; a2 += e*x0.z; a3 += e*x0.w;
            a4 += e*x1.x; a5 += e*x1.y; a6 += e*x1.z; a7 += e*x1.w;
        }
        float* yp = y + dm*II;
        atomicAdd(yp+0,a0); atomicAdd(yp+1,a1); atomicAdd(yp+2,a2); atomicAdd(yp+3,a3);
        atomicAdd(yp+4,a4); atomicAdd(yp+5,a5); atomicAdd(yp+6,a6); atomicAdd(yp+7,a7);
    }
    __syncthreads();

    // ---- g: v2 = squash(s2) ----
    if (tid < DD*OO*2) {
        const float v = s_squash<MM*II>(W, y, tid);
        v_l[(tid >> 5)*OO + ((tid >> 1) & 15)] = v;
    }
    __syncthreads();

    // ---- h: z_acc += z2 ----
    #pragma unroll
    for (int k = 0; k < 5; ++k) {
        const int s = tid + k*NT;
        const int d = s >> 8, mi = s & 255;
        const int m = mi >> 3, i = mi & 7;
        const float* wp = W + ((size_t)(d*MM + m)*OO) * II + i;
        const float* vp = v_l + d*OO;
        float acc = 0.f;
        #pragma unroll
        for (int o = 0; o < OO; ++o) acc += wp[o*II] * vp[o];
        z[s] += acc;                    // b2 = x . (z1+z2)
    }
    __syncthreads();

    // ---- i: final softmax over P, thread-local per (d,m); e[] in registers ----
    if (tid < DD*MM) {
        const int m = tid & 31;
        const float4* zp = (const float4*)(z + tid*II);
        const float4 z0 = zp[0], z1v = zp[1];
        const float* xr = xs + m*XS;
        float e[PP];
        float se = 0.f;
        #pragma unroll
        for (int p = 0; p < PP; ++p) {
            const float4* xp = (const float4*)(xr + p*II);
            e[p] = __expf(dot8(xp[0], xp[1], z0, z1v));
            se += e[p];
        }
        const float rs = 1.f / se;
        float a0=0.f,a1=0.f,a2=0.f,a3=0.f,a4=0.f,a5=0.f,a6=0.f,a7=0.f;
        #pragma unroll
        for (int p = 0; p < PP; ++p) {
            const float c = e[p] * rs;
            const float4* xp = (const float4*)(xr + p*II);
            const float4 x0 = xp[0], x1 = xp[1];
            a0 += c*x0.x; a1 += c*x0.y; a2 += c*x0.z; a3 += c*x0.w;
            a4 += c*x1.x; a5 += c*x1.y; a6 += c*x1.z; a7 += c*x1.w;
        }
        float4* yo = (float4*)(y + tid*II);
        yo[0] = make_float4(a0,a1,a2,a3);
        yo[1] = make_float4(a4,a5,a6,a7);
    }
    __syncthreads();

    // ---- j: out = squash(s3) ----
    if (tid < DD*OO*2) {
        const float r = s_squash<MM*II>(W, y, tid);
        if ((tid & 1) == 0)
            out[(size_t)bidx * (DD*OO) + (tid >> 5)*OO + ((tid >> 1) & 15)] = r;
    }
}

extern "C" void kernel_launch(void* const* d_in, const int* in_sizes, int n_in,
                              void* d_out, int out_size, void* d_ws, size_t ws_size,
                              hipStream_t stream) {
    (void)in_sizes; (void)n_in; (void)out_size; (void)d_ws; (void)ws_size;
    const float* x = (const float*)d_in[0];  // (B, M, P, I)
    const float* W = (const float*)d_in[1];  // (1, D, M, 1, O, I)
    float* out = (float*)d_out;              // (B, D, O)
    caps_routing<<<dim3(BB), dim3(NT), 0, stream>>>(x, W, out);
}

// Round 5
// 78.182 us; speedup vs baseline: 1.3605x; 1.3605x over previous
//
#include <hip/hip_runtime.h>
#include <math.h>

// CapsShapeLayer: B=256, D=10, M=32, P=36, I=8, O=16, 3 routing iters
// Design R5: one block per batch element, 10 waves, wave w owns d=w.
// Only 3 __syncthreads in the whole kernel; everything else is wave-local
// (shuffle reductions + in-wave LDS ordering).
#define BB 256
#define DD 10
#define MM 32
#define PP 36
#define II 8
#define OO 16
#define NT 640        // 10 waves = one per d
#define XS 292        // xs per-m stride in floats (= 4*73, 73 odd -> banks spread, 16B aligned)
#define RS 37         // rinv row stride: 37 mod 32 = 5, gcd(5,32)=1 -> conflict-free

__device__ __forceinline__ float dot8(const float4 a0, const float4 a1,
                                      const float4 b0, const float4 b1) {
    return a0.x*b0.x + a0.y*b0.y + a0.z*b0.z + a0.w*b0.w
         + a1.x*b1.x + a1.y*b1.y + a1.z*b1.z + a1.w*b1.w;
}

__global__ void __launch_bounds__(NT) caps_routing(
    const float* __restrict__ x,   // (B, M, P, I)
    const float* __restrict__ W,   // (D, M, O, I)
    float* __restrict__ out)       // (B, D, O)
{
    const int bidx = blockIdx.x;
    const int tid  = threadIdx.x;
    const int wave = tid >> 6;          // == d owned by this wave (0..9)
    const int lane = tid & 63;
    const float* __restrict__ xb = x + (size_t)bidx * (MM*PP*II);

    __shared__ __align__(16) float xs  [MM*XS];     // 37376 B  x staged once
    __shared__ __align__(16) float z   [DD*MM*II];  // 10240 B  z1, then z1+z2 (wave-private slices)
    __shared__ __align__(16) float y   [DD*MM*II];  // 10240 B  y scratch (wave-private slices)
    __shared__ __align__(16) float ybar[MM*II];     //  1024 B
    __shared__ __align__(16) float rinv[MM*RS];     //  4736 B
    // total 63616 B

    // ======== stage 0: x -> LDS (all threads) + ybar from global (threads<256) ========
    {
        const float4* xg = (const float4*)xb;
        #pragma unroll
        for (int k = 0; k < 4; ++k) {                 // 2304 float4 over 640 thr
            const int t = tid + k*NT;
            if (t < MM*72) {
                const int m = t / 72, r = t - m*72;
                *(float4*)(xs + m*XS + 4*r) = xg[t];
            }
        }
        if (tid < MM*II) {                            // ybar[m,i] = 0.1 * sum_p x  (c1 = 1/D exact)
            const int m = tid >> 3, i = tid & 7;
            const float* xr = xb + m*(PP*II) + i;
            float acc = 0.f;
            #pragma unroll 6
            for (int p = 0; p < PP; ++p) acc += xr[p*II];
            ybar[tid] = 0.1f * acc;
        }
    }
    __syncthreads();                                  // BARRIER 1

    // ======== per-wave (d = wave): s1 -> v1 -> z1 ========
    {
        const int d = wave;
        const int o = lane & 15, q = lane >> 4;       // o in bits 0-3, m-quarter in bits 4-5
        float s1 = 0.f;
        #pragma unroll
        for (int j = 0; j < 8; ++j) {
            const int m = q*8 + j;
            const float4* wp = (const float4*)(W + ((size_t)((d*MM + m)*OO + o)) * II);
            const float4* yp = (const float4*)(ybar + m*II);
            s1 += dot8(wp[0], wp[1], yp[0], yp[1]);
        }
        s1 += __shfl_xor(s1, 16, 64);                 // reduce over m-quarters
        s1 += __shfl_xor(s1, 32, 64);
        float sq = s1 * s1;                           // squash: sum s^2 over o (bits 0-3)
        sq += __shfl_xor(sq, 1, 64);
        sq += __shfl_xor(sq, 2, 64);
        sq += __shfl_xor(sq, 4, 64);
        sq += __shfl_xor(sq, 8, 64);
        const float v1 = (sq / (1.f + sq)) * (s1 / sqrtf(sq + 1e-7f));
        float vv[OO];                                 // broadcast v1[o2] from lane o2
        #pragma unroll
        for (int o2 = 0; o2 < OO; ++o2) vv[o2] = __shfl(v1, o2, 64);
        #pragma unroll
        for (int k = 0; k < 4; ++k) {                 // z1[d,m,i] = sum_o W*v1
            const int mi = k*64 + lane;
            const int m = mi >> 3, i = mi & 7;
            const float* wp = W + ((size_t)(d*MM + m)*OO) * II + i;
            float acc = 0.f;
            #pragma unroll
            for (int o2 = 0; o2 < OO; ++o2) acc += wp[o2*II] * vv[o2];
            z[d*(MM*II) + mi] = acc;
        }
    }
    __syncthreads();                                  // BARRIER 2 (rinv needs all d's z1)

    // ======== rinv[m,p] = 1 / sum_d exp(x.z1)  (all 640 threads; |b|<~4 -> no max) ========
    #pragma unroll
    for (int k = 0; k < 2; ++k) {
        const int t = tid + k*NT;
        if (t < MM*PP) {
            const int m = t / PP, p = t - m*PP;
            const float4* xp = (const float4*)(xs + m*XS + p*II);
            const float4 x0 = xp[0], x1 = xp[1];
            float se = 0.f;
            #pragma unroll
            for (int d2 = 0; d2 < DD; ++d2) {
                const float4* zp = (const float4*)(z + (d2*MM + m)*II);
                se += __expf(dot8(x0, x1, zp[0], zp[1]));
            }
            rinv[m*RS + p] = 1.0f / se;
        }
    }
    __syncthreads();                                  // BARRIER 3 (last barrier)

    // ======== per-wave tail: y2 -> s2 -> v2 -> z2 -> final softmax(P) -> s3 -> out ========
    {
        const int d  = wave;
        float* __restrict__ zd = z + d*(MM*II);
        float* __restrict__ yd = y + d*(MM*II);

        // ---- y2[m,i] = sum_p exp(x.z1)*rinv * x : lane = (m, i-half) ----
        const int mL = lane >> 1, ih = lane & 1;
        {
            const float4* zp = (const float4*)(zd + mL*II);
            const float4 z0 = zp[0], z1v = zp[1];
            const float* xr = xs + mL*XS;
            const float* rr = rinv + mL*RS;
            float a0=0.f, a1=0.f, a2=0.f, a3=0.f;
            #pragma unroll 4
            for (int p = 0; p < PP; ++p) {
                const float4* xp = (const float4*)(xr + p*II);
                const float4 x0 = xp[0], x1 = xp[1];
                const float e = __expf(dot8(x0, x1, z0, z1v)) * rr[p];
                const float4 xh = ih ? x1 : x0;
                a0 += e*xh.x; a1 += e*xh.y; a2 += e*xh.z; a3 += e*xh.w;
            }
            *(float4*)(yd + mL*II + ih*4) = make_float4(a0,a1,a2,a3);
        }
        // (in-wave LDS write->read: ordered by lgkmcnt, no barrier)

        // ---- s2 -> v2 (same shuffle pattern as s1) ----
        const int o = lane & 15, q = lane >> 4;
        float s2 = 0.f;
        #pragma unroll
        for (int j = 0; j < 8; ++j) {
            const int m = q*8 + j;
            const float4* wp = (const float4*)(W + ((size_t)((d*MM + m)*OO + o)) * II);
            const float4* yp = (const float4*)(yd + m*II);
            s2 += dot8(wp[0], wp[1], yp[0], yp[1]);
        }
        s2 += __shfl_xor(s2, 16, 64);
        s2 += __shfl_xor(s2, 32, 64);
        float sq = s2 * s2;
        sq += __shfl_xor(sq, 1, 64);
        sq += __shfl_xor(sq, 2, 64);
        sq += __shfl_xor(sq, 4, 64);
        sq += __shfl_xor(sq, 8, 64);
        const float v2 = (sq / (1.f + sq)) * (s2 / sqrtf(sq + 1e-7f));
        float vv[OO];
        #pragma unroll
        for (int o2 = 0; o2 < OO; ++o2) vv[o2] = __shfl(v2, o2, 64);

        // ---- z_acc = z1 + z2 (wave-private LDS RMW) ----
        #pragma unroll
        for (int k = 0; k < 4; ++k) {
            const int mi = k*64 + lane;
            const int m = mi >> 3, i = mi & 7;
            const float* wp = W + ((size_t)(d*MM + m)*OO) * II + i;
            float acc = 0.f;
            #pragma unroll
            for (int o2 = 0; o2 < OO; ++o2) acc += wp[o2*II] * vv[o2];
            zd[mi] += acc;
        }

        // ---- final softmax over P (per (d,m), wave-local, single pass) ----
        {
            const float4* zp = (const float4*)(zd + mL*II);
            const float4 z0 = zp[0], z1v = zp[1];
            const float* xr = xs + mL*XS;
            float se = 0.f;
            float a0=0.f, a1=0.f, a2=0.f, a3=0.f;
            #pragma unroll 4
            for (int p = 0; p < PP; ++p) {
                const float4* xp = (const float4*)(xr + p*II);
                const float4 x0 = xp[0], x1 = xp[1];
                const float e = __expf(dot8(x0, x1, z0, z1v));
                se += e;
                const float4 xh = ih ? x1 : x0;
                a0 += e*xh.x; a1 += e*xh.y; a2 += e*xh.z; a3 += e*xh.w;
            }
            const float rs = 1.f / se;
            *(float4*)(yd + mL*II + ih*4) = make_float4(a0*rs, a1*rs, a2*rs, a3*rs);
        }

        // ---- s3 -> squash -> out ----
        float s3 = 0.f;
        #pragma unroll
        for (int j = 0; j < 8; ++j) {
            const int m = q*8 + j;
            const float4* wp = (const float4*)(W + ((size_t)((d*MM + m)*OO + o)) * II);
            const float4* yp = (const float4*)(yd + m*II);
            s3 += dot8(wp[0], wp[1], yp[0], yp[1]);
        }
        s3 += __shfl_xor(s3, 16, 64);
        s3 += __shfl_xor(s3, 32, 64);
        float sq3 = s3 * s3;
        sq3 += __shfl_xor(sq3, 1, 64);
        sq3 += __shfl_xor(sq3, 2, 64);
        sq3 += __shfl_xor(sq3, 4, 64);
        sq3 += __shfl_xor(sq3, 8, 64);
        const float r = (sq3 / (1.f + sq3)) * (s3 / sqrtf(sq3 + 1e-7f));
        if (lane < OO)
            out[(size_t)bidx * (DD*OO) + d*OO + o] = r;
    }
}

extern "C" void kernel_launch(void* const* d_in, const int* in_sizes, int n_in,
                              void* d_out, int out_size, void* d_ws, size_t ws_size,
                              hipStream_t stream) {
    (void)in_sizes; (void)n_in; (void)out_size; (void)d_ws; (void)ws_size;
    const float* x = (const float*)d_in[0];  // (B, M, P, I)
    const float* W = (const float*)d_in[1];  // (1, D, M, 1, O, I)
    float* out = (float*)d_out;              // (B, D, O)
    caps_routing<<<dim3(BB), dim3(NT), 0, stream>>>(x, W, out);
}